// Round 7
// baseline (5221.922 us; speedup 1.0000x reference)
//
#include <hip/hip_runtime.h>
#include <hip/hip_fp16.h>
#include <math.h>

#define NNODES 100000
#define NEDGES 3200000
#define NFEAT  512
#define NHID   256
#define NCLASS 40
#define DPB    64                        // dsts per bucket
#define NBUCK  1563                      // ceil(NNODES / DPB)
#define SBUCK  782                       // src buckets of 128 (src>>7)
#define TILE   16384                     // edges per bin block
#define NTILE  196                       // ceil(NEDGES / TILE)

typedef short  bf16x8 __attribute__((ext_vector_type(8)));
typedef unsigned short u16x8 __attribute__((ext_vector_type(8)));
typedef float  f32x4  __attribute__((ext_vector_type(4)));
typedef _Float16 half4 __attribute__((ext_vector_type(4)));

__device__ inline unsigned short f2bf_rne(float f) {
    unsigned u = __float_as_uint(f);
    unsigned r = (u + 0x7FFFu + ((u >> 16) & 1u)) >> 16;
    return (unsigned short)r;
}
__device__ inline float bf2f(unsigned short h) {
    return __uint_as_float((unsigned)h << 16);
}

// ============ W1 transpose + hi/lo bf16 split ===============================
__global__ __launch_bounds__(256) void w1_split_kernel(
    const float* __restrict__ W1, unsigned short* __restrict__ hi,
    unsigned short* __restrict__ lo)
{
    const int i = blockIdx.x * 256 + threadIdx.x;
    if (i >= NFEAT * NHID) return;
    const int k = i >> 8;
    const int n = i & 255;
    const float f = W1[i];
    const unsigned short h = f2bf_rne(f);
    const unsigned short l = f2bf_rne(f - bf2f(h));
    hi[n * NFEAT + k] = h;
    lo[n * NFEAT + k] = l;
}

// ============ GEMM1 via MFMA: h0 = fp16(x @ W1 + b1) ========================
__global__ __launch_bounds__(256) void gemm1_mfma_kernel(
    const float* __restrict__ x, const unsigned short* __restrict__ Bhi,
    const unsigned short* __restrict__ Blo, const float* __restrict__ b1,
    _Float16* __restrict__ h0)
{
    __shared__ __align__(16) unsigned short As_hi[64 * 40];
    __shared__ __align__(16) unsigned short As_lo[64 * 40];
    const int t = threadIdx.x;
    const int lane = t & 63;
    const int w = t >> 6;
    const int row0 = blockIdx.x * 64;
    const int wn0 = w * 64;
    const int fr = lane & 15;
    const int fq = lane >> 4;
    const int srow = t >> 2;
    const int skq  = (t & 3) * 8;
    const int grow = row0 + srow;
    const float* xp = x + (size_t)grow * NFEAT + skq;
    unsigned short* ah = &As_hi[srow * 40 + skq];
    unsigned short* al = &As_lo[srow * 40 + skq];

    f32x4 acc[4][4] = {};

    for (int k0 = 0; k0 < NFEAT; k0 += 32) {
        float v[8];
        if (grow < NNODES) {
            const float4 u0 = *(const float4*)(xp + k0);
            const float4 u1 = *(const float4*)(xp + k0 + 4);
            v[0] = u0.x; v[1] = u0.y; v[2] = u0.z; v[3] = u0.w;
            v[4] = u1.x; v[5] = u1.y; v[6] = u1.z; v[7] = u1.w;
        } else {
            #pragma unroll
            for (int j = 0; j < 8; ++j) v[j] = 0.f;
        }
        u16x8 hv, lv;
        #pragma unroll
        for (int j = 0; j < 8; ++j) {
            const unsigned short h = f2bf_rne(v[j]);
            hv[j] = h;
            lv[j] = f2bf_rne(v[j] - bf2f(h));
        }
        __syncthreads();
        *(u16x8*)ah = hv;
        *(u16x8*)al = lv;
        __syncthreads();

        bf16x8 a_h[4], a_l[4];
        #pragma unroll
        for (int mt = 0; mt < 4; ++mt) {
            const int off = (mt * 16 + fr) * 40 + fq * 8;
            a_h[mt] = *(const bf16x8*)&As_hi[off];
            a_l[mt] = *(const bf16x8*)&As_lo[off];
        }
        bf16x8 b_h[4], b_l[4];
        #pragma unroll
        for (int nt = 0; nt < 4; ++nt) {
            const int n = wn0 + nt * 16 + fr;
            const size_t boff = (size_t)n * NFEAT + k0 + fq * 8;
            b_h[nt] = *(const bf16x8*)(Bhi + boff);
            b_l[nt] = *(const bf16x8*)(Blo + boff);
        }
        #pragma unroll
        for (int mt = 0; mt < 4; ++mt)
            #pragma unroll
            for (int nt = 0; nt < 4; ++nt) {
                acc[mt][nt] = __builtin_amdgcn_mfma_f32_16x16x32_bf16(
                    a_h[mt], b_h[nt], acc[mt][nt], 0, 0, 0);
                acc[mt][nt] = __builtin_amdgcn_mfma_f32_16x16x32_bf16(
                    a_h[mt], b_l[nt], acc[mt][nt], 0, 0, 0);
                acc[mt][nt] = __builtin_amdgcn_mfma_f32_16x16x32_bf16(
                    a_l[mt], b_h[nt], acc[mt][nt], 0, 0, 0);
            }
    }
    #pragma unroll
    for (int mt = 0; mt < 4; ++mt)
        #pragma unroll
        for (int nt = 0; nt < 4; ++nt) {
            const int c = wn0 + nt * 16 + fr;
            const float bias = b1[c];
            const int r0 = row0 + mt * 16 + fq * 4;
            #pragma unroll
            for (int r = 0; r < 4; ++r) {
                const int row = r0 + r;
                if (row < NNODES)
                    h0[(size_t)row * NHID + c] = (_Float16)(acc[mt][nt][r] + bias);
            }
        }
}

// ============ GEMM2: h2 = fp16(h1 @ W2 + b2)  [N,256] x [256,40] ============
__global__ __launch_bounds__(256) void gemm2_kernel(
    const float* __restrict__ h1, const float* __restrict__ W2,
    const float* __restrict__ b2, _Float16* __restrict__ h2)
{
    __shared__ float Bs[NHID * NCLASS];
    __shared__ float As[64][33];
    const int t = threadIdx.x;
    const int row0 = blockIdx.x * 64;
    for (int i = t; i < NHID * NCLASS; i += 256) Bs[i] = W2[i];
    const int r  = t & 63;
    const int cg = (t >> 6) * 10;
    const int am = t >> 2, ak = (t & 3) * 8;
    float acc[10] = {};
    for (int k0 = 0; k0 < NHID; k0 += 32) {
        __syncthreads();
        float4 v0 = make_float4(0.f,0.f,0.f,0.f), v1 = v0;
        const int arow = row0 + am;
        if (arow < NNODES) {
            v0 = *(const float4*)(h1 + (size_t)arow * NHID + k0 + ak);
            v1 = *(const float4*)(h1 + (size_t)arow * NHID + k0 + ak + 4);
        }
        As[am][ak + 0] = v0.x; As[am][ak + 1] = v0.y;
        As[am][ak + 2] = v0.z; As[am][ak + 3] = v0.w;
        As[am][ak + 4] = v1.x; As[am][ak + 5] = v1.y;
        As[am][ak + 6] = v1.z; As[am][ak + 7] = v1.w;
        __syncthreads();
        #pragma unroll
        for (int k = 0; k < 32; ++k) {
            const float a = As[r][k];
            #pragma unroll
            for (int j = 0; j < 10; ++j)
                acc[j] += a * Bs[(k0 + k) * NCLASS + cg + j];
        }
    }
    const int arow = row0 + r;
    if (arow < NNODES) {
        #pragma unroll
        for (int j = 0; j < 10; ++j)
            h2[(size_t)arow * NCLASS + cg + j] = (_Float16)(acc[j] + b2[cg + j]);
    }
}

// ============ CSR build: two-level binned counting sort (DPB=64) ============
__global__ __launch_bounds__(256) void csr_init_kernel(
    int* __restrict__ bhist, int* __restrict__ rowptr)
{
    const int i = blockIdx.x * 256 + threadIdx.x;
    if (i < NBUCK) bhist[i] = 0;
    if (i == 0) rowptr[NNODES] = NEDGES;
}

__global__ __launch_bounds__(256) void bin_count_kernel(
    const int* __restrict__ ei, int* __restrict__ bhist)
{
    __shared__ int h[NBUCK];
    const int t = threadIdx.x;
    for (int i = t; i < NBUCK; i += 256) h[i] = 0;
    __syncthreads();
    const int base = blockIdx.x * TILE;
    #pragma unroll 1
    for (int it = 0; it < TILE / 1024; ++it) {
        const int e = base + it * 1024 + t * 4;
        if (e + 3 < NEDGES) {
            const int4 d = *(const int4*)(ei + e);
            atomicAdd(&h[d.x >> 6], 1);
            atomicAdd(&h[d.y >> 6], 1);
            atomicAdd(&h[d.z >> 6], 1);
            atomicAdd(&h[d.w >> 6], 1);
        } else {
            for (int j = e; j < NEDGES; ++j) atomicAdd(&h[ei[j] >> 6], 1);
        }
    }
    __syncthreads();
    for (int i = t; i < NBUCK; i += 256)
        if (h[i]) atomicAdd(&bhist[i], h[i]);
}

// exclusive scan of 1563 bucket counts: 1024 thr x 2 elems
__global__ __launch_bounds__(1024) void bucket_scan_kernel(
    const int* __restrict__ bhist, int* __restrict__ bbase, int* __restrict__ bcur)
{
    __shared__ int s[1024];
    const int t = threadIdx.x;
    const int i0 = t * 2;
    const int v0 = (i0 < NBUCK) ? bhist[i0] : 0;
    const int v1 = (i0 + 1 < NBUCK) ? bhist[i0 + 1] : 0;
    s[t] = v0 + v1;
    __syncthreads();
    for (int o = 1; o < 1024; o <<= 1) {
        const int u = (t >= o) ? s[t - o] : 0;
        __syncthreads();
        s[t] += u;
        __syncthreads();
    }
    const int excl = s[t] - (v0 + v1);
    if (i0 < NBUCK)     { bbase[i0] = excl;          bcur[i0] = excl; }
    if (i0 + 1 < NBUCK) { bbase[i0 + 1] = excl + v0; bcur[i0 + 1] = excl + v0; }
    if (t == 1023) bbase[NBUCK] = s[1023];
}

// packed: .x = (local_dst << 17) | src   (local<64 -> 6b, src<131072 -> 17b)
__global__ __launch_bounds__(256) void bin_scatter_kernel(
    const int* __restrict__ ei, const float* __restrict__ ew,
    int* __restrict__ bcur, int2* __restrict__ binned)
{
    __shared__ int h[NBUCK];
    __shared__ int cur[NBUCK];
    const int t = threadIdx.x;
    for (int i = t; i < NBUCK; i += 256) h[i] = 0;
    __syncthreads();
    const int base = blockIdx.x * TILE;
    #pragma unroll 1
    for (int it = 0; it < TILE / 1024; ++it) {
        const int e = base + it * 1024 + t * 4;
        if (e + 3 < NEDGES) {
            const int4 d = *(const int4*)(ei + e);
            atomicAdd(&h[d.x >> 6], 1);
            atomicAdd(&h[d.y >> 6], 1);
            atomicAdd(&h[d.z >> 6], 1);
            atomicAdd(&h[d.w >> 6], 1);
        } else {
            for (int j = e; j < NEDGES; ++j) atomicAdd(&h[ei[j] >> 6], 1);
        }
    }
    __syncthreads();
    for (int i = t; i < NBUCK; i += 256)
        if (h[i]) cur[i] = atomicAdd(&bcur[i], h[i]);
    __syncthreads();
    #pragma unroll 1
    for (int it = 0; it < TILE / 1024; ++it) {
        const int e = base + it * 1024 + t * 4;
        if (e + 3 < NEDGES) {
            const int4   d = *(const int4*)(ei + e);
            const int4   s = *(const int4*)(ei + NEDGES + e);
            const float4 w = *(const float4*)(ew + e);
            int p0 = atomicAdd(&cur[d.x >> 6], 1);
            int p1 = atomicAdd(&cur[d.y >> 6], 1);
            int p2 = atomicAdd(&cur[d.z >> 6], 1);
            int p3 = atomicAdd(&cur[d.w >> 6], 1);
            binned[p0] = make_int2(((d.x & 63) << 17) | s.x, __float_as_int(w.x));
            binned[p1] = make_int2(((d.y & 63) << 17) | s.y, __float_as_int(w.y));
            binned[p2] = make_int2(((d.z & 63) << 17) | s.z, __float_as_int(w.z));
            binned[p3] = make_int2(((d.w & 63) << 17) | s.w, __float_as_int(w.w));
        } else {
            for (int j = e; j < NEDGES; ++j) {
                const int dj = ei[j];
                const int p = atomicAdd(&cur[dj >> 6], 1);
                binned[p] = make_int2(((dj & 63) << 17) | ei[NEDGES + j],
                                      __float_as_int(ew[j]));
            }
        }
    }
}

// one block per bucket: exact dst-order pairs + rowptr (for spmm2)
__global__ __launch_bounds__(256) void regroup_kernel(
    const int* __restrict__ bbase, const int2* __restrict__ binned,
    int* __restrict__ rowptr, int2* __restrict__ pairs)
{
    __shared__ int cnt[DPB];
    __shared__ int s[DPB];
    const int b = blockIdx.x;
    const int t = threadIdx.x;
    const int d0 = b * DPB;
    const int nd = (NNODES - d0 < DPB) ? (NNODES - d0) : DPB;
    if (t < DPB) cnt[t] = 0;
    __syncthreads();
    const int lo = bbase[b], hiE = bbase[b + 1];
    for (int idx = lo + t; idx < hiE; idx += 256)
        atomicAdd(&cnt[binned[idx].x >> 17], 1);
    __syncthreads();
    const int v = (t < DPB) ? cnt[t] : 0;
    if (t < DPB) s[t] = v;
    __syncthreads();
    for (int o = 1; o < DPB; o <<= 1) {
        const int u = (t >= o && t < DPB) ? s[t - o] : 0;
        __syncthreads();
        if (t < DPB) s[t] += u;
        __syncthreads();
    }
    if (t < nd) {
        const int base = lo + s[t] - v;
        rowptr[d0 + t] = base;
        cnt[t] = base;
    }
    __syncthreads();
    for (int idx = lo + t; idx < hiE; idx += 256) {
        const int2 e = binned[idx];
        const int l = e.x >> 17;
        const int pos = atomicAdd(&cnt[l], 1);
        pairs[pos] = make_int2(e.x & 0x1FFFF, e.y);
    }
}

// one block per bucket: counting-sort bucket edges by src>>7 -> spairs
__global__ __launch_bounds__(256) void sort2_kernel(
    const int* __restrict__ bbase, const int2* __restrict__ binned,
    int2* __restrict__ spairs)
{
    __shared__ int sh[SBUCK + 2];
    __shared__ int sc[SBUCK + 2];
    __shared__ int ss[256];
    const int b = blockIdx.x;
    const int t = threadIdx.x;
    for (int i = t; i < SBUCK + 2; i += 256) sh[i] = 0;
    __syncthreads();
    const int lo = bbase[b], hiE = bbase[b + 1];
    for (int idx = lo + t; idx < hiE; idx += 256)
        atomicAdd(&sh[(binned[idx].x & 0x1FFFF) >> 7], 1);
    __syncthreads();
    // scan 784 entries: thread t owns [4t, 4t+4)
    int v[4] = {0, 0, 0, 0};
    int tsum = 0;
    if (t < 196) {
        #pragma unroll
        for (int j = 0; j < 4; ++j) { v[j] = sh[4 * t + j]; tsum += v[j]; }
    }
    ss[t] = tsum;
    __syncthreads();
    for (int o = 1; o < 256; o <<= 1) {
        const int u = (t >= o) ? ss[t - o] : 0;
        __syncthreads();
        ss[t] += u;
        __syncthreads();
    }
    if (t < 196) {
        int run = ss[t] - tsum;
        #pragma unroll
        for (int j = 0; j < 4; ++j) { sc[4 * t + j] = lo + run; run += v[j]; }
    }
    __syncthreads();
    for (int idx = lo + t; idx < hiE; idx += 256) {
        const int2 e = binned[idx];
        const int sb = (e.x & 0x1FFFF) >> 7;
        const int pos = atomicAdd(&sc[sb], 1);
        spairs[pos] = e;
    }
}

// ============ SpMM1: block per 64-dst bucket, src-sorted edges, LDS acc =====
// thread t owns feature t exclusively; LDS atomic add = ds_add_f32, bank t%32
__global__ __launch_bounds__(256) void spmm1_lds_kernel(
    const int* __restrict__ bbase, const int2* __restrict__ spairs,
    const _Float16* __restrict__ h0, float* __restrict__ h1)
{
    __shared__ float acc[DPB * NHID];    // 64 KB
    const int b = blockIdx.x;
    const int t = threadIdx.x;
    float4* a4 = (float4*)acc;
    #pragma unroll
    for (int i = 0; i < 16; ++i)
        a4[i * 256 + t] = make_float4(0.f, 0.f, 0.f, 0.f);
    const int lo = bbase[b], hiE = bbase[b + 1];
    __syncthreads();
    const _Float16* hp = h0 + t;
    int idx = lo;
    for (; idx + 3 < hiE; idx += 4) {
        const int2 e0 = spairs[idx];
        const int2 e1 = spairs[idx + 1];
        const int2 e2 = spairs[idx + 2];
        const int2 e3 = spairs[idx + 3];
        const float v0 = (float)hp[(size_t)(e0.x & 0x1FFFF) * NHID];
        const float v1 = (float)hp[(size_t)(e1.x & 0x1FFFF) * NHID];
        const float v2 = (float)hp[(size_t)(e2.x & 0x1FFFF) * NHID];
        const float v3 = (float)hp[(size_t)(e3.x & 0x1FFFF) * NHID];
        atomicAdd(&acc[(e0.x >> 17) * NHID + t], v0 * __int_as_float(e0.y));
        atomicAdd(&acc[(e1.x >> 17) * NHID + t], v1 * __int_as_float(e1.y));
        atomicAdd(&acc[(e2.x >> 17) * NHID + t], v2 * __int_as_float(e2.y));
        atomicAdd(&acc[(e3.x >> 17) * NHID + t], v3 * __int_as_float(e3.y));
    }
    for (; idx < hiE; ++idx) {
        const int2 e0 = spairs[idx];
        const float v0 = (float)hp[(size_t)(e0.x & 0x1FFFF) * NHID];
        atomicAdd(&acc[(e0.x >> 17) * NHID + t], v0 * __int_as_float(e0.y));
    }
    __syncthreads();
    const int d0 = b * DPB;
    #pragma unroll 4
    for (int d = 0; d < DPB; ++d) {
        const int row = d0 + d;
        if (row < NNODES)
            h1[(size_t)row * NHID + t] = fmaxf(acc[d * NHID + t], 0.f);
    }
}

// ============ SpMM2 (fp16 gather) + fused log-softmax: wave per dst =========
__global__ __launch_bounds__(256) void spmm2_csr_kernel(
    const int* __restrict__ rowptr, const int2* __restrict__ pairs,
    const _Float16* __restrict__ h2, float* __restrict__ out)
{
    const int dst  = blockIdx.x * 4 + (threadIdx.x >> 6);
    const int lane = threadIdx.x & 63;
    if (dst >= NNODES) return;
    const int beg = rowptr[dst], end = rowptr[dst + 1];
    float a0 = 0.f, a1 = 0.f;
    int j = beg;
    for (; j + 1 < end; j += 2) {
        const int2 p0 = pairs[j];
        const int2 p1 = pairs[j + 1];
        float v0 = 0.f, v1 = 0.f;
        if (lane < NCLASS) {
            v0 = (float)h2[(size_t)p0.x * NCLASS + lane];
            v1 = (float)h2[(size_t)p1.x * NCLASS + lane];
        }
        a0 = fmaf(v0, __int_as_float(p0.y), a0);
        a1 = fmaf(v1, __int_as_float(p1.y), a1);
    }
    if (j < end) {
        const int2 p0 = pairs[j];
        float v0 = 0.f;
        if (lane < NCLASS) v0 = (float)h2[(size_t)p0.x * NCLASS + lane];
        a0 = fmaf(v0, __int_as_float(p0.y), a0);
    }
    const float acc = a0 + a1;
    float val = (lane < NCLASS) ? acc : -INFINITY;
    float m = val;
    #pragma unroll
    for (int o = 32; o >= 1; o >>= 1) m = fmaxf(m, __shfl_xor(m, o));
    float ex = (lane < NCLASS) ? expf(val - m) : 0.f;
    float s = ex;
    #pragma unroll
    for (int o = 32; o >= 1; o >>= 1) s += __shfl_xor(s, o);
    if (lane < NCLASS) out[(size_t)dst * NCLASS + lane] = val - m - logf(s);
}

// ============ launch ========================================================
extern "C" void kernel_launch(void* const* d_in, const int* in_sizes, int n_in,
                              void* d_out, int out_size, void* d_ws, size_t ws_size,
                              hipStream_t stream)
{
    const float* x  = (const float*)d_in[0];
    const int*   ei = (const int*)d_in[1];   // [2,E]: dst row then src row
    const float* ew = (const float*)d_in[2];
    const float* W1 = (const float*)d_in[3];
    const float* b1 = (const float*)d_in[4];
    const float* W2 = (const float*)d_in[5];
    const float* b2 = (const float*)d_in[6];
    float* out = (float*)d_out;

    char* ws = (char*)d_ws;
    const size_t H_BYTES = (size_t)NNODES * NHID * 4;        // 102,400,000
    _Float16* h0 = (_Float16*)(ws);          // 51.2 MB fp16, [0, 51.2M)
    int2* spairs = (int2*)(ws + 51200000);   // 25.6 MB, free upper half of h0 slot
    float* h1 = (float*)(ws + H_BYTES);      // 102.4 MB fp32
    int2* binned = (int2*)(ws + H_BYTES);    // aliases h1 (dead before spmm1)
    int2* pairs  = (int2*)(ws + 2 * H_BYTES);                // 25.6 MB
    char* region = ws + 2 * H_BYTES + (size_t)NEDGES * 8;
    // W1T (512 KB) dead after gemm1; CSR arrays occupy the same bytes after.
    unsigned short* W1T_hi = (unsigned short*)(region);           // 262,144 B
    unsigned short* W1T_lo = (unsigned short*)(region + 262144);  // 262,144 B
    int* rowptr = (int*)(region);                            // 400,016 B
    int* bhist  = (int*)(region + 400016);                   // 6,252 B
    int* bbase  = (int*)(region + 406272);                   // 6,256 B
    int* bcur   = (int*)(region + 412528);                   // 6,252 B
    _Float16* h2 = (_Float16*)(ws);    // 8 MB fp16, aliases h0 (dead after spmm1)

    // 1. W1 -> transposed bf16 hi/lo split; h0 = fp16(x @ W1 + b1)
    w1_split_kernel<<<(NFEAT * NHID + 255) / 256, 256, 0, stream>>>(W1, W1T_hi, W1T_lo);
    gemm1_mfma_kernel<<<(NNODES + 63) / 64, 256, 0, stream>>>(x, W1T_hi, W1T_lo, b1, h0);
    // 2. CSR build (W1T dead from here): dst-bucket sort (64 dsts/bucket)
    csr_init_kernel<<<(NBUCK + 255) / 256, 256, 0, stream>>>(bhist, rowptr);
    bin_count_kernel<<<NTILE, 256, 0, stream>>>(ei, bhist);
    bucket_scan_kernel<<<1, 1024, 0, stream>>>(bhist, bbase, bcur);
    bin_scatter_kernel<<<NTILE, 256, 0, stream>>>(ei, ew, bcur, binned);
    // 2a. exact dst-order pairs + rowptr (for spmm2)
    regroup_kernel<<<NBUCK, 256, 0, stream>>>(bbase, binned, rowptr, pairs);
    // 2b. src-sorted-within-bucket list (for spmm1 L2 locality)
    sort2_kernel<<<NBUCK, 256, 0, stream>>>(bbase, binned, spairs);
    // 3. h1 = relu(spmm(h0)) — bucket-LDS accumulate over src-sorted edges
    spmm1_lds_kernel<<<NBUCK, 256, 0, stream>>>(bbase, spairs, h0, h1);
    // 4. h2 = fp16(h1 @ W2 + b2)
    gemm2_kernel<<<(NNODES + 63) / 64, 256, 0, stream>>>(h1, W2, b2, h2);
    // 5. out = logsoftmax(spmm(h2)) — fp16 gather
    spmm2_csr_kernel<<<(NNODES + 3) / 4, 256, 0, stream>>>(rowptr, pairs, h2, out);
}

// Round 8
// 713.333 us; speedup vs baseline: 7.3205x; 7.3205x over previous
//
#include <hip/hip_runtime.h>
#include <hip/hip_fp16.h>
#include <math.h>

#define NNODES 100000
#define NEDGES 3200000
#define NFEAT  512
#define NHID   256
#define NCLASS 40
#define DPB    128                       // dsts per bucket
#define NBUCK  782                       // ceil(NNODES / DPB)
#define TILE   16384                     // edges per bin block
#define NTILE  196                       // ceil(NEDGES / TILE)

typedef _Float16 half8 __attribute__((ext_vector_type(8)));
typedef _Float16 half4 __attribute__((ext_vector_type(4)));
typedef float  f32x4  __attribute__((ext_vector_type(4)));

// ============ W1 transpose + fp16 convert: W1[512][256] -> W1T[256][512] ====
__global__ __launch_bounds__(256) void w1_f16_kernel(
    const float* __restrict__ W1, _Float16* __restrict__ W1T)
{
    const int i = blockIdx.x * 256 + threadIdx.x;     // 131072 total
    if (i >= NFEAT * NHID) return;
    const int k = i >> 8;        // row of W1 (K)
    const int n = i & 255;       // col of W1 (N)
    W1T[n * NFEAT + k] = (_Float16)W1[i];
}

// ============ GEMM1 via f16 MFMA (single pass): h0 = fp16(x @ W1 + b1) ======
// block = 256 thr = 4 waves; tile 64 rows x 256 cols; wave w owns cols w*64..+63
__global__ __launch_bounds__(256) void gemm1_f16_kernel(
    const float* __restrict__ x, const _Float16* __restrict__ Bt,
    const float* __restrict__ b1, _Float16* __restrict__ h0)
{
    __shared__ __align__(16) _Float16 As[64 * 40];   // [row][k], pad 40
    const int t = threadIdx.x;
    const int lane = t & 63;
    const int w = t >> 6;
    const int row0 = blockIdx.x * 64;
    const int wn0 = w * 64;
    const int fr = lane & 15;        // fragment row/col index
    const int fq = lane >> 4;        // k-group
    const int srow = t >> 2;             // 0..63
    const int skq  = (t & 3) * 8;        // 0,8,16,24
    const int grow = row0 + srow;
    const float* xp = x + (size_t)grow * NFEAT + skq;
    _Float16* ap = &As[srow * 40 + skq];

    f32x4 acc[4][4] = {};

    for (int k0 = 0; k0 < NFEAT; k0 += 32) {
        // ---- load + convert A slice (8 floats -> fp16) ----
        half8 hv;
        if (grow < NNODES) {
            const float4 u0 = *(const float4*)(xp + k0);
            const float4 u1 = *(const float4*)(xp + k0 + 4);
            hv[0] = (_Float16)u0.x; hv[1] = (_Float16)u0.y;
            hv[2] = (_Float16)u0.z; hv[3] = (_Float16)u0.w;
            hv[4] = (_Float16)u1.x; hv[5] = (_Float16)u1.y;
            hv[6] = (_Float16)u1.z; hv[7] = (_Float16)u1.w;
        } else {
            #pragma unroll
            for (int j = 0; j < 8; ++j) hv[j] = (_Float16)0.f;
        }
        __syncthreads();                 // prior iteration's frag reads done
        *(half8*)ap = hv;
        __syncthreads();                 // LDS tile ready

        // ---- A frags from LDS ----
        half8 a_f[4];
        #pragma unroll
        for (int mt = 0; mt < 4; ++mt)
            a_f[mt] = *(const half8*)&As[(mt * 16 + fr) * 40 + fq * 8];
        // ---- B frags direct from global (256 KB, L2-hot) ----
        half8 b_f[4];
        #pragma unroll
        for (int nt = 0; nt < 4; ++nt) {
            const int n = wn0 + nt * 16 + fr;
            b_f[nt] = *(const half8*)(Bt + (size_t)n * NFEAT + k0 + fq * 8);
        }
        // ---- 16 MFMAs ----
        #pragma unroll
        for (int mt = 0; mt < 4; ++mt)
            #pragma unroll
            for (int nt = 0; nt < 4; ++nt)
                acc[mt][nt] = __builtin_amdgcn_mfma_f32_16x16x32_f16(
                    a_f[mt], b_f[nt], acc[mt][nt], 0, 0, 0);
    }
    // ---- epilogue: C/D layout col = lane&15, row = (lane>>4)*4 + r ----
    #pragma unroll
    for (int mt = 0; mt < 4; ++mt)
        #pragma unroll
        for (int nt = 0; nt < 4; ++nt) {
            const int c = wn0 + nt * 16 + fr;
            const float bias = b1[c];
            const int r0 = row0 + mt * 16 + fq * 4;
            #pragma unroll
            for (int r = 0; r < 4; ++r) {
                const int row = r0 + r;
                if (row < NNODES)
                    h0[(size_t)row * NHID + c] = (_Float16)(acc[mt][nt][r] + bias);
            }
        }
}

// ============ GEMM2: h2 = fp16(h1 @ W2 + b2)  [N,256] x [256,40] ============
__global__ __launch_bounds__(256) void gemm2_kernel(
    const float* __restrict__ h1, const float* __restrict__ W2,
    const float* __restrict__ b2, _Float16* __restrict__ h2)
{
    __shared__ float Bs[NHID * NCLASS];
    __shared__ float As[64][33];
    const int t = threadIdx.x;
    const int row0 = blockIdx.x * 64;
    for (int i = t; i < NHID * NCLASS; i += 256) Bs[i] = W2[i];
    const int r  = t & 63;
    const int cg = (t >> 6) * 10;
    const int am = t >> 2, ak = (t & 3) * 8;
    float acc[10] = {};
    for (int k0 = 0; k0 < NHID; k0 += 32) {
        __syncthreads();
        float4 v0 = make_float4(0.f,0.f,0.f,0.f), v1 = v0;
        const int arow = row0 + am;
        if (arow < NNODES) {
            v0 = *(const float4*)(h1 + (size_t)arow * NHID + k0 + ak);
            v1 = *(const float4*)(h1 + (size_t)arow * NHID + k0 + ak + 4);
        }
        As[am][ak + 0] = v0.x; As[am][ak + 1] = v0.y;
        As[am][ak + 2] = v0.z; As[am][ak + 3] = v0.w;
        As[am][ak + 4] = v1.x; As[am][ak + 5] = v1.y;
        As[am][ak + 6] = v1.z; As[am][ak + 7] = v1.w;
        __syncthreads();
        #pragma unroll
        for (int k = 0; k < 32; ++k) {
            const float a = As[r][k];
            #pragma unroll
            for (int j = 0; j < 10; ++j)
                acc[j] += a * Bs[(k0 + k) * NCLASS + cg + j];
        }
    }
    const int arow = row0 + r;
    if (arow < NNODES) {
        #pragma unroll
        for (int j = 0; j < 10; ++j)
            h2[(size_t)arow * NCLASS + cg + j] = (_Float16)(acc[j] + b2[cg + j]);
    }
}

// ============ CSR build: two-level binned counting sort =====================
__global__ __launch_bounds__(256) void csr_init_kernel(
    int* __restrict__ bhist, int* __restrict__ rowptr)
{
    const int i = blockIdx.x * 256 + threadIdx.x;
    if (i < NBUCK) bhist[i] = 0;
    if (i == 0) rowptr[NNODES] = NEDGES;
}

__global__ __launch_bounds__(256) void bin_count_kernel(
    const int* __restrict__ ei, int* __restrict__ bhist)
{
    __shared__ int h[NBUCK];
    const int t = threadIdx.x;
    for (int i = t; i < NBUCK; i += 256) h[i] = 0;
    __syncthreads();
    const int base = blockIdx.x * TILE;
    #pragma unroll 1
    for (int it = 0; it < TILE / 1024; ++it) {
        const int e = base + it * 1024 + t * 4;
        if (e + 3 < NEDGES) {
            const int4 d = *(const int4*)(ei + e);
            atomicAdd(&h[d.x >> 7], 1);
            atomicAdd(&h[d.y >> 7], 1);
            atomicAdd(&h[d.z >> 7], 1);
            atomicAdd(&h[d.w >> 7], 1);
        } else {
            for (int j = e; j < NEDGES; ++j) atomicAdd(&h[ei[j] >> 7], 1);
        }
    }
    __syncthreads();
    for (int i = t; i < NBUCK; i += 256)
        if (h[i]) atomicAdd(&bhist[i], h[i]);
}

__global__ __launch_bounds__(1024) void bucket_scan_kernel(
    const int* __restrict__ bhist, int* __restrict__ bbase, int* __restrict__ bcur)
{
    __shared__ int s[1024];
    const int t = threadIdx.x;
    const int v = (t < NBUCK) ? bhist[t] : 0;
    s[t] = v;
    __syncthreads();
    for (int o = 1; o < 1024; o <<= 1) {
        const int u = (t >= o) ? s[t - o] : 0;
        __syncthreads();
        s[t] += u;
        __syncthreads();
    }
    if (t < NBUCK) { bbase[t] = s[t] - v; bcur[t] = s[t] - v; }
    if (t == 1023) bbase[NBUCK] = s[1023];
}

// packed: .x = (local_dst << 17) | src
__global__ __launch_bounds__(256) void bin_scatter_kernel(
    const int* __restrict__ ei, const float* __restrict__ ew,
    int* __restrict__ bcur, int2* __restrict__ binned)
{
    __shared__ int h[NBUCK];
    __shared__ int cur[NBUCK];
    const int t = threadIdx.x;
    for (int i = t; i < NBUCK; i += 256) h[i] = 0;
    __syncthreads();
    const int base = blockIdx.x * TILE;
    #pragma unroll 1
    for (int it = 0; it < TILE / 1024; ++it) {
        const int e = base + it * 1024 + t * 4;
        if (e + 3 < NEDGES) {
            const int4 d = *(const int4*)(ei + e);
            atomicAdd(&h[d.x >> 7], 1);
            atomicAdd(&h[d.y >> 7], 1);
            atomicAdd(&h[d.z >> 7], 1);
            atomicAdd(&h[d.w >> 7], 1);
        } else {
            for (int j = e; j < NEDGES; ++j) atomicAdd(&h[ei[j] >> 7], 1);
        }
    }
    __syncthreads();
    for (int i = t; i < NBUCK; i += 256)
        if (h[i]) cur[i] = atomicAdd(&bcur[i], h[i]);
    __syncthreads();
    #pragma unroll 1
    for (int it = 0; it < TILE / 1024; ++it) {
        const int e = base + it * 1024 + t * 4;
        if (e + 3 < NEDGES) {
            const int4   d = *(const int4*)(ei + e);
            const int4   s = *(const int4*)(ei + NEDGES + e);
            const float4 w = *(const float4*)(ew + e);
            int p0 = atomicAdd(&cur[d.x >> 7], 1);
            int p1 = atomicAdd(&cur[d.y >> 7], 1);
            int p2 = atomicAdd(&cur[d.z >> 7], 1);
            int p3 = atomicAdd(&cur[d.w >> 7], 1);
            binned[p0] = make_int2(((d.x & 127) << 17) | s.x, __float_as_int(w.x));
            binned[p1] = make_int2(((d.y & 127) << 17) | s.y, __float_as_int(w.y));
            binned[p2] = make_int2(((d.z & 127) << 17) | s.z, __float_as_int(w.z));
            binned[p3] = make_int2(((d.w & 127) << 17) | s.w, __float_as_int(w.w));
        } else {
            for (int j = e; j < NEDGES; ++j) {
                const int dj = ei[j];
                const int p = atomicAdd(&cur[dj >> 7], 1);
                binned[p] = make_int2(((dj & 127) << 17) | ei[NEDGES + j],
                                      __float_as_int(ew[j]));
            }
        }
    }
}

__global__ __launch_bounds__(256) void regroup_kernel(
    const int* __restrict__ bbase, const int2* __restrict__ binned,
    int* __restrict__ rowptr, int2* __restrict__ pairs)
{
    __shared__ int cnt[DPB];
    __shared__ int s[DPB];
    const int b = blockIdx.x;
    const int t = threadIdx.x;
    const int d0 = b * DPB;
    const int nd = (NNODES - d0 < DPB) ? (NNODES - d0) : DPB;
    if (t < DPB) cnt[t] = 0;
    __syncthreads();
    const int lo = bbase[b], hiE = bbase[b + 1];
    for (int idx = lo + t; idx < hiE; idx += 256)
        atomicAdd(&cnt[binned[idx].x >> 17], 1);
    __syncthreads();
    const int v = (t < DPB) ? cnt[t] : 0;
    if (t < DPB) s[t] = v;
    __syncthreads();
    for (int o = 1; o < DPB; o <<= 1) {
        const int u = (t >= o && t < DPB) ? s[t - o] : 0;
        __syncthreads();
        if (t < DPB) s[t] += u;
        __syncthreads();
    }
    if (t < nd) {
        const int base = lo + s[t] - v;
        rowptr[d0 + t] = base;
        cnt[t] = base;
    }
    __syncthreads();
    for (int idx = lo + t; idx < hiE; idx += 256) {
        const int2 e = binned[idx];
        const int l = e.x >> 17;
        const int pos = atomicAdd(&cnt[l], 1);
        pairs[pos] = make_int2(e.x & 0x1FFFF, e.y);
    }
}

// ============ SpMM1 full-row fp16 gather (+fused ReLU): wave per dst ========
__global__ __launch_bounds__(256) void spmm1_f16_kernel(
    const int* __restrict__ rowptr, const int2* __restrict__ pairs,
    const _Float16* __restrict__ h0, float* __restrict__ h1)
{
    const int dst  = blockIdx.x * 4 + (threadIdx.x >> 6);
    const int lane = threadIdx.x & 63;
    if (dst >= NNODES) return;
    const int beg = rowptr[dst], end = rowptr[dst + 1];
    const _Float16* base = h0 + lane * 4;
    float a0[4] = {0.f, 0.f, 0.f, 0.f};
    float a1[4] = {0.f, 0.f, 0.f, 0.f};
    int j = beg;
    for (; j + 1 < end; j += 2) {
        const int2 p0 = pairs[j];
        const int2 p1 = pairs[j + 1];
        const half4 v0 = *(const half4*)(base + (size_t)p0.x * NHID);
        const half4 v1 = *(const half4*)(base + (size_t)p1.x * NHID);
        const float w0 = __int_as_float(p0.y), w1 = __int_as_float(p1.y);
        #pragma unroll
        for (int k = 0; k < 4; ++k) {
            a0[k] = fmaf((float)v0[k], w0, a0[k]);
            a1[k] = fmaf((float)v1[k], w1, a1[k]);
        }
    }
    if (j < end) {
        const int2 p0 = pairs[j];
        const half4 v0 = *(const half4*)(base + (size_t)p0.x * NHID);
        const float w0 = __int_as_float(p0.y);
        #pragma unroll
        for (int k = 0; k < 4; ++k)
            a0[k] = fmaf((float)v0[k], w0, a0[k]);
    }
    float4 o;
    o.x = fmaxf(a0[0] + a1[0], 0.f);
    o.y = fmaxf(a0[1] + a1[1], 0.f);
    o.z = fmaxf(a0[2] + a1[2], 0.f);
    o.w = fmaxf(a0[3] + a1[3], 0.f);
    *(float4*)(h1 + (size_t)dst * NHID + lane * 4) = o;
}

// ============ SpMM2 (fp16 gather) + fused log-softmax: wave per dst =========
__global__ __launch_bounds__(256) void spmm2_csr_kernel(
    const int* __restrict__ rowptr, const int2* __restrict__ pairs,
    const _Float16* __restrict__ h2, float* __restrict__ out)
{
    const int dst  = blockIdx.x * 4 + (threadIdx.x >> 6);
    const int lane = threadIdx.x & 63;
    if (dst >= NNODES) return;
    const int beg = rowptr[dst], end = rowptr[dst + 1];
    float a0 = 0.f, a1 = 0.f;
    int j = beg;
    for (; j + 1 < end; j += 2) {
        const int2 p0 = pairs[j];
        const int2 p1 = pairs[j + 1];
        float v0 = 0.f, v1 = 0.f;
        if (lane < NCLASS) {
            v0 = (float)h2[(size_t)p0.x * NCLASS + lane];
            v1 = (float)h2[(size_t)p1.x * NCLASS + lane];
        }
        a0 = fmaf(v0, __int_as_float(p0.y), a0);
        a1 = fmaf(v1, __int_as_float(p1.y), a1);
    }
    if (j < end) {
        const int2 p0 = pairs[j];
        float v0 = 0.f;
        if (lane < NCLASS) v0 = (float)h2[(size_t)p0.x * NCLASS + lane];
        a0 = fmaf(v0, __int_as_float(p0.y), a0);
    }
    const float acc = a0 + a1;
    float val = (lane < NCLASS) ? acc : -INFINITY;
    float m = val;
    #pragma unroll
    for (int o = 32; o >= 1; o >>= 1) m = fmaxf(m, __shfl_xor(m, o));
    float ex = (lane < NCLASS) ? expf(val - m) : 0.f;
    float s = ex;
    #pragma unroll
    for (int o = 32; o >= 1; o >>= 1) s += __shfl_xor(s, o);
    if (lane < NCLASS) out[(size_t)dst * NCLASS + lane] = val - m - logf(s);
}

// ============ launch ========================================================
extern "C" void kernel_launch(void* const* d_in, const int* in_sizes, int n_in,
                              void* d_out, int out_size, void* d_ws, size_t ws_size,
                              hipStream_t stream)
{
    const float* x  = (const float*)d_in[0];
    const int*   ei = (const int*)d_in[1];   // [2,E]: dst row then src row
    const float* ew = (const float*)d_in[2];
    const float* W1 = (const float*)d_in[3];
    const float* b1 = (const float*)d_in[4];
    const float* W2 = (const float*)d_in[5];
    const float* b2 = (const float*)d_in[6];
    float* out = (float*)d_out;

    char* ws = (char*)d_ws;
    const size_t H_BYTES = (size_t)NNODES * NHID * 4;        // 102,400,000
    _Float16* h0 = (_Float16*)(ws);          // 51.2 MB fp16
    float* h1 = (float*)(ws + H_BYTES);      // 102.4 MB fp32
    int2* binned = (int2*)(ws + H_BYTES);    // aliases h1 (dead before spmm1)
    int2* pairs  = (int2*)(ws + 2 * H_BYTES);                // 25.6 MB
    char* region = ws + 2 * H_BYTES + (size_t)NEDGES * 8;
    // W1T (256 KB) dead after gemm1; CSR arrays occupy the same bytes after.
    _Float16* W1T = (_Float16*)(region);                     // 262,144 B
    int* rowptr = (int*)(region);                            // 400,016 B
    int* bhist  = (int*)(region + 400016);                   // 3,128 B
    int* bbase  = (int*)(region + 403152);                   // 3,132 B
    int* bcur   = (int*)(region + 406288);                   // 3,128 B
    _Float16* h2 = (_Float16*)(ws);    // 8 MB fp16, aliases h0 (dead after spmm1)

    // 1. W1 -> transposed fp16; h0 = fp16(x @ W1 + b1) single-pass f16 MFMA
    w1_f16_kernel<<<(NFEAT * NHID + 255) / 256, 256, 0, stream>>>(W1, W1T);
    gemm1_f16_kernel<<<(NNODES + 63) / 64, 256, 0, stream>>>(x, W1T, b1, h0);
    // 2. CSR build: binned counting sort (W1T dead from here)
    csr_init_kernel<<<(NBUCK + 255) / 256, 256, 0, stream>>>(bhist, rowptr);
    bin_count_kernel<<<NTILE, 256, 0, stream>>>(ei, bhist);
    bucket_scan_kernel<<<1, 1024, 0, stream>>>(bhist, bbase, bcur);
    bin_scatter_kernel<<<NTILE, 256, 0, stream>>>(ei, ew, bcur, binned);
    regroup_kernel<<<NBUCK, 256, 0, stream>>>(bbase, binned, rowptr, pairs);
    // 3. h1 = relu(spmm(h0)) — single full-row fp16-gather pass
    spmm1_f16_kernel<<<(NNODES + 3) / 4, 256, 0, stream>>>(rowptr, pairs, h0, h1);
    // 4. h2 = fp16(h1 @ W2 + b2)
    gemm2_kernel<<<(NNODES + 63) / 64, 256, 0, stream>>>(h1, W2, b2, h2);
    // 5. out = logsoftmax(spmm(h2)) — fp16 gather
    spmm2_csr_kernel<<<(NNODES + 3) / 4, 256, 0, stream>>>(rowptr, pairs, h2, out);
}